// Round 2
// baseline (315.354 us; speedup 1.0000x reference)
//
#include <hip/hip_runtime.h>

#define KTAGS 32
#define BOSI 30
#define EOSI 31

// XOR-swizzle within 32-lane groups: lane j reads lane j^PAT (BitMode offset)
template<int PAT>
__device__ __forceinline__ float swz_xor(float v) {
    return __int_as_float(__builtin_amdgcn_ds_swizzle(__float_as_int(v), (PAT << 10) | 0x1F));
}
// broadcast group-local lane 0 (and=0, or=0, xor=0)
__device__ __forceinline__ float bcast0(float v) {
    return __int_as_float(__builtin_amdgcn_ds_swizzle(__float_as_int(v), 0x0000));
}

// fill uv[K] = u from lane tag^K, K = 1..31 (all independent, pipeline on DS pipe)
template<int K>
struct SWZ {
    static __device__ __forceinline__ void run(float u, float (&uv)[32]) {
        uv[K] = swz_xor<K>(u);
        SWZ<K + 1>::run(u, uv);
    }
};
template<>
struct SWZ<32> {
    static __device__ __forceinline__ void run(float, float (&)[32]) {}
};

__global__ __launch_bounds__(256) void crf_fwd_kernel(const float* __restrict__ em,
                                                      const float* __restrict__ tr,
                                                      float* __restrict__ out,
                                                      int T) {
    __shared__ float E[KTAGS * KTAGS];  // exp(transitions)
    const int tid = threadIdx.x;

#pragma unroll
    for (int k = 0; k < 4; ++k) {
        int idx = tid + k * 256;
        E[idx] = __expf(tr[idx]);
    }
    __syncthreads();

    const int tag = tid & 31;
    const int b = blockIdx.x * 8 + (tid >> 5);  // 8 sequences per block

    // per-lane permuted row of exp(T): Ep[k] = expT[tag, tag^k]
    float Ep[32];
#pragma unroll
    for (int k = 0; k < 32; ++k) Ep[k] = E[tag * 32 + (tag ^ k)];

    const float tEOS = tr[EOSI * 32 + tag];  // transitions[EOS, tag]
    const float* eptr = em + (size_t)b * T * KTAGS + tag;

    // scaled-exp state: u = exp(alpha - M). init: 1 at BOS, exp(-10000) -> 0 elsewhere
    float u = (tag == BOSI) ? 1.f : 0.f;
    float logC = 0.f;  // accumulated log-scale M

    float ebuf[8];
#pragma unroll
    for (int q = 0; q < 8; ++q) ebuf[q] = eptr[q * 32];

    const int NC = T / 8;  // 64 chunks of 8 steps
    for (int c = 0; c < NC; ++c) {
        // exp(emissions) for this chunk — off the serial chain
        float eex[8];
#pragma unroll
        for (int q = 0; q < 8; ++q) eex[q] = __expf(ebuf[q]);

        // prefetch next chunk (clamped redundant load on last chunk)
        const int cn = (c + 1 < NC) ? (c + 1) : c;
#pragma unroll
        for (int q = 0; q < 8; ++q) ebuf[q] = eptr[(size_t)cn * 256 + q * 32];

        // 8 recurrence steps: u = (E @ u) * exp(e_t) — no transcendentals in chain
#pragma unroll
        for (int q = 0; q < 8; ++q) {
            float uv[32];
            uv[0] = u;
            SWZ<1>::run(u, uv);
            float acc[8];
#pragma unroll
            for (int p = 0; p < 8; ++p) acc[p] = uv[p] * Ep[p];
#pragma unroll
            for (int k = 8; k < 32; ++k) acc[k & 7] = fmaf(uv[k], Ep[k], acc[k & 7]);
            float y = ((acc[0] + acc[1]) + (acc[2] + acc[3])) +
                      ((acc[4] + acc[5]) + (acc[6] + acc[7]));
            u = y * eex[q];
        }

        // renormalize every 8 steps: u[tag0] > 0 after step 1; keeps u in fp32 range
        float r = bcast0(u);
        u *= __builtin_amdgcn_rcpf(r);
        logC += __logf(r);
    }

    // alpha_T = log(u) + logC; terminal lse over the 32-lane group
    float alpha = __logf(u) + logC;  // u==0 -> -inf, handled by lse below
    float t = alpha + tEOS;
    float mx = t;
    mx = fmaxf(mx, swz_xor<1>(mx));
    mx = fmaxf(mx, swz_xor<2>(mx));
    mx = fmaxf(mx, swz_xor<4>(mx));
    mx = fmaxf(mx, swz_xor<8>(mx));
    mx = fmaxf(mx, swz_xor<16>(mx));
    float s = __expf(t - mx);
    s += swz_xor<1>(s);
    s += swz_xor<2>(s);
    s += swz_xor<4>(s);
    s += swz_xor<8>(s);
    s += swz_xor<16>(s);
    float res = mx + __logf(s);
    if (tag == 0) out[b] = res;
}

extern "C" void kernel_launch(void* const* d_in, const int* in_sizes, int n_in,
                              void* d_out, int out_size, void* d_ws, size_t ws_size,
                              hipStream_t stream) {
    const float* em = (const float*)d_in[0];
    const float* tr = (const float*)d_in[1];
    float* out = (float*)d_out;

    const int T = 512;
    const int B = in_sizes[0] / (T * KTAGS);  // 2048
    const int blocks = B / 8;                 // 256 blocks x 256 threads (8 seqs/block)

    crf_fwd_kernel<<<blocks, 256, 0, stream>>>(em, tr, out, T);
}

// Round 3
// 219.009 us; speedup vs baseline: 1.4399x; 1.4399x over previous
//
#include <hip/hip_runtime.h>

#define KTAGS 32
#define BOSI 30
#define EOSI 31

// XOR-swizzle within 32-lane groups (involution — direction-free)
template<int PAT>
__device__ __forceinline__ float swz_xor(float v) {
    return __int_as_float(__builtin_amdgcn_ds_swizzle(__float_as_int(v), (PAT << 10) | 0x1F));
}
// broadcast group-local lane 0
__device__ __forceinline__ float bcast0(float v) {
    return __int_as_float(__builtin_amdgcn_ds_swizzle(__float_as_int(v), 0x0000));
}
// DPP rotate within 16-lane rows (direction probed at runtime)
template<int R>
__device__ __forceinline__ float dpp_ror(float v) {
    return __int_as_float(__builtin_amdgcn_update_dpp(0, __float_as_int(v), 0x120 | R, 0xF, 0xF, true));
}

// acc[r&3] += ror<r>(s) * Ep[r], r = 0..15 (r=0 is identity)
template<int R>
struct ROT {
    static __device__ __forceinline__ void run(float s, const float (&Ep)[16], float (&acc)[4]) {
        float t;
        if constexpr (R == 0) t = s;
        else t = dpp_ror<R>(s);
        acc[R & 3] = fmaf(t, Ep[R], acc[R & 3]);
        ROT<R + 1>::run(s, Ep, acc);
    }
};
template<>
struct ROT<16> {
    static __device__ __forceinline__ void run(float, const float (&)[16], float (&)[4]) {}
};

__global__ __launch_bounds__(256, 1) void crf_fwd_kernel(const float* __restrict__ em,
                                                         const float* __restrict__ tr,
                                                         float* __restrict__ out,
                                                         int T) {
    const int tid = threadIdx.x;
    const int tag = tid & 31;
    const int j = tag & 15;        // position within 16-lane DPP row
    const int g = tag >> 4;        // which 16-block of tags this lane is in
    const int b = blockIdx.x * 8 + (tid >> 5);  // 8 sequences per block

    // probe DPP row_ror:1 direction with the lane-id pattern (wave-uniform result)
    int probe = __builtin_amdgcn_update_dpp(0, j, 0x121, 0xF, 0xF, true);
    const bool dirplus = (probe == ((j + 1) & 15));

    // register-resident permuted exp(transitions) rows — NO LDS, NO reloads.
    // Eo[r]: own 16-block (cols 16*g + ...), Ex[r]: other 16-block.
    float Eo[16], Ex[16];
#pragma unroll
    for (int r = 0; r < 16; ++r) {
        int jr = dirplus ? ((j + r) & 15) : ((j - r) & 15);
        Eo[r] = __expf(tr[tag * 32 + jr + 16 * g]);
        Ex[r] = __expf(tr[tag * 32 + jr + 16 * (1 - g)]);
    }

    const float tEOS = tr[EOSI * 32 + tag];  // transitions[EOS, tag]
    const float* eptr = em + (size_t)b * T * KTAGS + tag;

    // scaled-exp state: u = exp(alpha - M)
    float u = (tag == BOSI) ? 1.f : 0.f;
    float logC = 0.f;

    float ebuf[8];
#pragma unroll
    for (int q = 0; q < 8; ++q) ebuf[q] = eptr[q * 32];

    const int NC = T / 8;
    for (int c = 0; c < NC; ++c) {
        // exp(emissions) for this chunk — independent of the serial chain
        float eex[8];
#pragma unroll
        for (int q = 0; q < 8; ++q) eex[q] = __expf(ebuf[q]);

        const int cn = (c + 1 < NC) ? (c + 1) : c;
#pragma unroll
        for (int q = 0; q < 8; ++q) ebuf[q] = eptr[(size_t)cn * 256 + q * 32];

        // 8 recurrence steps: u = (E @ u) * exp(e_t)
        // per step: 1 ds_swizzle + 30 DPP rotations + 32 fma
#pragma unroll
        for (int q = 0; q < 8; ++q) {
            float v = swz_xor<16>(u);  // other 16-block's u (latency hidden by own-pass)
            float acc[4] = {0.f, 0.f, 0.f, 0.f};
            ROT<0>::run(u, Eo, acc);   // own-block contributions
            ROT<0>::run(v, Ex, acc);   // other-block contributions
            float y = (acc[0] + acc[1]) + (acc[2] + acc[3]);
            u = y * eex[q];
        }

        // renormalize every 8 steps
        float r = bcast0(u);
        u *= __builtin_amdgcn_rcpf(r);
        logC += __logf(r);
    }

    // alpha_T = log(u) + logC; terminal lse over the 32-lane group
    float alpha = __logf(u) + logC;
    float t = alpha + tEOS;
    float mx = t;
    mx = fmaxf(mx, swz_xor<1>(mx));
    mx = fmaxf(mx, swz_xor<2>(mx));
    mx = fmaxf(mx, swz_xor<4>(mx));
    mx = fmaxf(mx, swz_xor<8>(mx));
    mx = fmaxf(mx, swz_xor<16>(mx));
    float s = __expf(t - mx);
    s += swz_xor<1>(s);
    s += swz_xor<2>(s);
    s += swz_xor<4>(s);
    s += swz_xor<8>(s);
    s += swz_xor<16>(s);
    float res = mx + __logf(s);
    if (tag == 0) out[b] = res;
}

extern "C" void kernel_launch(void* const* d_in, const int* in_sizes, int n_in,
                              void* d_out, int out_size, void* d_ws, size_t ws_size,
                              hipStream_t stream) {
    const float* em = (const float*)d_in[0];
    const float* tr = (const float*)d_in[1];
    float* out = (float*)d_out;

    const int T = 512;
    const int B = in_sizes[0] / (T * KTAGS);  // 2048
    const int blocks = B / 8;                 // 256 blocks x 256 threads

    crf_fwd_kernel<<<blocks, 256, 0, stream>>>(em, tr, out, T);
}

// Round 4
// 203.511 us; speedup vs baseline: 1.5496x; 1.0762x over previous
//
#include <hip/hip_runtime.h>

#define KTAGS 32
#define BOSI 30
#define EOSI 31

// XOR-swizzle within 32-lane groups (involution — direction-free)
template<int PAT>
__device__ __forceinline__ float swz_xor(float v) {
    return __int_as_float(__builtin_amdgcn_ds_swizzle(__float_as_int(v), (PAT << 10) | 0x1F));
}
// broadcast group-local lane 0
__device__ __forceinline__ float bcast0(float v) {
    return __int_as_float(__builtin_amdgcn_ds_swizzle(__float_as_int(v), 0x0000));
}

// Fused DPP+FMA: acc += ror<R>(src) * coef — single VOP2 instruction with DPP word.
// R must be a string literal "1".."15".
#define FMAC_R(acc, src, coef, R) \
    asm("v_fmac_f32 %0, %1, %2 row_ror:" R " row_mask:0xf bank_mask:0xf" \
        : "+v"(acc) : "v"(src), "v"(coef))
#define MUL_R(dst, src, coef, R) \
    asm("v_mul_f32 %0, %1, %2 row_ror:" R " row_mask:0xf bank_mask:0xf" \
        : "=v"(dst) : "v"(src), "v"(coef))

// one half-pass: acc[r&3] (+)= ror<r>(s) * Ep[r], r=0..15
// FIRST=true initializes acc[0..3] via muls (r=0..3), rest fmac.
template<bool FIRST>
__device__ __forceinline__ void half_pass(float s, const float (&Ep)[16], float (&a0)[4]) {
    if constexpr (FIRST) {
        a0[0] = s * Ep[0];
        MUL_R(a0[1], s, Ep[1], "1");
        MUL_R(a0[2], s, Ep[2], "2");
        MUL_R(a0[3], s, Ep[3], "3");
    } else {
        a0[0] = fmaf(s, Ep[0], a0[0]);
        FMAC_R(a0[1], s, Ep[1], "1");
        FMAC_R(a0[2], s, Ep[2], "2");
        FMAC_R(a0[3], s, Ep[3], "3");
    }
    FMAC_R(a0[0], s, Ep[4], "4");
    FMAC_R(a0[1], s, Ep[5], "5");
    FMAC_R(a0[2], s, Ep[6], "6");
    FMAC_R(a0[3], s, Ep[7], "7");
    FMAC_R(a0[0], s, Ep[8], "8");
    FMAC_R(a0[1], s, Ep[9], "9");
    FMAC_R(a0[2], s, Ep[10], "10");
    FMAC_R(a0[3], s, Ep[11], "11");
    FMAC_R(a0[0], s, Ep[12], "12");
    FMAC_R(a0[1], s, Ep[13], "13");
    FMAC_R(a0[2], s, Ep[14], "14");
    FMAC_R(a0[3], s, Ep[15], "15");
}

__global__ __launch_bounds__(256, 1) void crf_fwd_kernel(const float* __restrict__ em,
                                                         const float* __restrict__ tr,
                                                         float* __restrict__ out,
                                                         int T) {
    const int tid = threadIdx.x;
    const int tag = tid & 31;
    const int j = tag & 15;        // position within 16-lane DPP row
    const int g = tag >> 4;        // which 16-block of tags this lane is in
    const int b = blockIdx.x * 8 + (tid >> 5);  // 8 sequences per block

    // probe DPP row_ror:1 direction with the lane-id pattern (wave-uniform result)
    int probe = __builtin_amdgcn_update_dpp(0, j, 0x121, 0xF, 0xF, true);
    const bool dirplus = (probe == ((j + 1) & 15));

    // register-resident permuted exp(transitions) rows — no LDS
    float Eo[16], Ex[16];
#pragma unroll
    for (int r = 0; r < 16; ++r) {
        int jr = dirplus ? ((j + r) & 15) : ((j - r) & 15);
        Eo[r] = __expf(tr[tag * 32 + jr + 16 * g]);
        Ex[r] = __expf(tr[tag * 32 + jr + 16 * (1 - g)]);
    }

    const float tEOS = tr[EOSI * 32 + tag];  // transitions[EOS, tag]
    const float* eptr = em + (size_t)b * T * KTAGS + tag;

    // scaled-exp state: u = exp(alpha - M)
    float u = (tag == BOSI) ? 1.f : 0.f;
    float logC = 0.f;

    float ebuf[8];
#pragma unroll
    for (int q = 0; q < 8; ++q) ebuf[q] = eptr[q * 32];

    const int NC = T / 8;
    for (int c = 0; c < NC; ++c) {
        // exp(emissions) for this chunk — independent of the serial chain
        float eex[8];
#pragma unroll
        for (int q = 0; q < 8; ++q) eex[q] = __expf(ebuf[q]);

        const int cn = (c + 1 < NC) ? (c + 1) : c;
#pragma unroll
        for (int q = 0; q < 8; ++q) ebuf[q] = eptr[(size_t)cn * 256 + q * 32];

        // 8 recurrence steps: u = (E @ u) * exp(e_t)
        // per step: 1 ds_swizzle + 32 fused dpp-fma + 3 add + 1 mul
#pragma unroll
        for (int q = 0; q < 8; ++q) {
            float v = swz_xor<16>(u);  // issue first; own-half pass hides DS latency
            float acc[4];
            half_pass<true>(u, Eo, acc);   // own 16-block
            half_pass<false>(v, Ex, acc);  // other 16-block
            float y = (acc[0] + acc[1]) + (acc[2] + acc[3]);
            u = y * eex[q];
        }

        // renormalize every 8 steps
        float r = bcast0(u);
        u *= __builtin_amdgcn_rcpf(r);
        logC += __logf(r);
    }

    // alpha_T = log(u) + logC; terminal lse over the 32-lane group
    float alpha = __logf(u) + logC;
    float t = alpha + tEOS;
    float mx = t;
    mx = fmaxf(mx, swz_xor<1>(mx));
    mx = fmaxf(mx, swz_xor<2>(mx));
    mx = fmaxf(mx, swz_xor<4>(mx));
    mx = fmaxf(mx, swz_xor<8>(mx));
    mx = fmaxf(mx, swz_xor<16>(mx));
    float s = __expf(t - mx);
    s += swz_xor<1>(s);
    s += swz_xor<2>(s);
    s += swz_xor<4>(s);
    s += swz_xor<8>(s);
    s += swz_xor<16>(s);
    float res = mx + __logf(s);
    if (tag == 0) out[b] = res;
}

extern "C" void kernel_launch(void* const* d_in, const int* in_sizes, int n_in,
                              void* d_out, int out_size, void* d_ws, size_t ws_size,
                              hipStream_t stream) {
    const float* em = (const float*)d_in[0];
    const float* tr = (const float*)d_in[1];
    float* out = (float*)d_out;

    const int T = 512;
    const int B = in_sizes[0] / (T * KTAGS);  // 2048
    const int blocks = B / 8;                 // 256 blocks x 256 threads

    crf_fwd_kernel<<<blocks, 256, 0, stream>>>(em, tr, out, T);
}

// Round 5
// 201.157 us; speedup vs baseline: 1.5677x; 1.0117x over previous
//
#include <hip/hip_runtime.h>

#define KTAGS 32
#define BOSI 30
#define EOSI 31

typedef unsigned int uint2v __attribute__((ext_vector_type(2)));

// XOR-swizzle within 32-lane groups (involution — direction-free). Fallback path.
template<int PAT>
__device__ __forceinline__ float swz_xor(float v) {
    return __int_as_float(__builtin_amdgcn_ds_swizzle(__float_as_int(v), (PAT << 10) | 0x1F));
}
// broadcast group-local lane 0 (fallback renorm)
__device__ __forceinline__ float bcast0(float v) {
    return __int_as_float(__builtin_amdgcn_ds_swizzle(__float_as_int(v), 0x0000));
}

// Fused DPP+FMA: acc += ror<R>(src) * coef — single VOP2 with DPP word.
#define FMAC_R(acc, src, coef, R) \
    asm("v_fmac_f32 %0, %1, %2 row_ror:" R " row_mask:0xf bank_mask:0xf" \
        : "+v"(acc) : "v"(src), "v"(coef))
#define MUL_R(dst, src, coef, R) \
    asm("v_mul_f32 %0, %1, %2 row_ror:" R " row_mask:0xf bank_mask:0xf" \
        : "=v"(dst) : "v"(src), "v"(coef))

// one half-pass: acc[r&3] (+)= ror<r>(s) * Ep[r], r=0..15
template<bool FIRST>
__device__ __forceinline__ void half_pass(float s, const float (&Ep)[16], float (&a0)[4]) {
    if constexpr (FIRST) {
        a0[0] = s * Ep[0];
        MUL_R(a0[1], s, Ep[1], "1");
        MUL_R(a0[2], s, Ep[2], "2");
        MUL_R(a0[3], s, Ep[3], "3");
    } else {
        a0[0] = fmaf(s, Ep[0], a0[0]);
        FMAC_R(a0[1], s, Ep[1], "1");
        FMAC_R(a0[2], s, Ep[2], "2");
        FMAC_R(a0[3], s, Ep[3], "3");
    }
    FMAC_R(a0[0], s, Ep[4], "4");
    FMAC_R(a0[1], s, Ep[5], "5");
    FMAC_R(a0[2], s, Ep[6], "6");
    FMAC_R(a0[3], s, Ep[7], "7");
    FMAC_R(a0[0], s, Ep[8], "8");
    FMAC_R(a0[1], s, Ep[9], "9");
    FMAC_R(a0[2], s, Ep[10], "10");
    FMAC_R(a0[3], s, Ep[11], "11");
    FMAC_R(a0[0], s, Ep[12], "12");
    FMAC_R(a0[1], s, Ep[13], "13");
    FMAC_R(a0[2], s, Ep[14], "14");
    FMAC_R(a0[3], s, Ep[15], "15");
}

#if __has_builtin(__builtin_amdgcn_permlane16_swap)
#define HAVE_PLSWAP 1
// tag^16 exchange via permlane16_swap: .x=[r0,r0,r2,r2], .y=[r1,r1,r3,r3]
__device__ __forceinline__ float xchg16_pl(float u, bool sel_even) {
    uint2v r = __builtin_amdgcn_permlane16_swap(__float_as_uint(u), __float_as_uint(u), false, false);
    return __uint_as_float(sel_even ? r.y : r.x);
}
// broadcast group-local u[15] to all 32 lanes: row_bcast15 then swap, take .y
__device__ __forceinline__ float gbcast15_pl(float u) {
    int t = __builtin_amdgcn_update_dpp(0, __float_as_int(u), 0x142, 0xF, 0xF, false);
    uint2v r = __builtin_amdgcn_permlane16_swap((unsigned)t, (unsigned)t, false, false);
    return __uint_as_float(r.y);
}
#else
#define HAVE_PLSWAP 0
#endif

// main scan loop; FAST = permlane path (probe-verified), else DS-swizzle path (R4-exact)
template<bool FAST>
__device__ __forceinline__ float run_scan(const float* eptr, const float (&Eo)[16],
                                          const float (&Ex)[16], int tag, bool sel_even,
                                          float& logC) {
    float u = (tag == BOSI) ? 1.f : 0.f;
    logC = 0.f;

    float ebuf[8];
#pragma unroll
    for (int q = 0; q < 8; ++q) ebuf[q] = eptr[q * 32];

    const int NC = 512 / 8;
    for (int c = 0; c < NC; ++c) {
        float eex[8];
#pragma unroll
        for (int q = 0; q < 8; ++q) eex[q] = __expf(ebuf[q]);

        const int cn = (c + 1 < NC) ? (c + 1) : c;
#pragma unroll
        for (int q = 0; q < 8; ++q) ebuf[q] = eptr[(size_t)cn * 256 + q * 32];

#pragma unroll
        for (int q = 0; q < 8; ++q) {
            float v;
#if HAVE_PLSWAP
            if constexpr (FAST) v = xchg16_pl(u, sel_even);
            else v = swz_xor<16>(u);
#else
            v = swz_xor<16>(u);
#endif
            float acc[4];
            half_pass<true>(u, Eo, acc);   // own 16-block
            half_pass<false>(v, Ex, acc);  // other 16-block
            float y = (acc[0] + acc[1]) + (acc[2] + acc[3]);
            u = y * eex[q];
        }

        // renormalize every 8 steps (any positive group-uniform scale is valid)
        float r;
#if HAVE_PLSWAP
        if constexpr (FAST) r = gbcast15_pl(u);
        else r = bcast0(u);
#else
        r = bcast0(u);
#endif
        u *= __builtin_amdgcn_rcpf(r);
        logC += __logf(r);
    }
    return u;
}

__global__ __launch_bounds__(256, 1) void crf_fwd_kernel(const float* __restrict__ em,
                                                         const float* __restrict__ tr,
                                                         float* __restrict__ out,
                                                         int T) {
    const int tid = threadIdx.x;
    const int tag = tid & 31;
    const int j = tag & 15;
    const int g = tag >> 4;
    const int b = blockIdx.x * 8 + (tid >> 5);

    // probe DPP row_ror:1 direction (verified technique from R3/R4)
    int probe = __builtin_amdgcn_update_dpp(0, j, 0x121, 0xF, 0xF, true);
    const bool dirplus = (probe == ((j + 1) & 15));

    // register-resident permuted exp(transitions) rows
    float Eo[16], Ex[16];
#pragma unroll
    for (int r = 0; r < 16; ++r) {
        int jr = dirplus ? ((j + r) & 15) : ((j - r) & 15);
        Eo[r] = __expf(tr[tag * 32 + jr + 16 * g]);
        Ex[r] = __expf(tr[tag * 32 + jr + 16 * (1 - g)]);
    }

    const float tEOS = tr[EOSI * 32 + tag];
    const float* eptr = em + (size_t)b * (size_t)T * KTAGS + tag;
    const bool sel_even = ((tag & 16) == 0);

    // runtime probe of permlane16_swap semantics; fall back to DS path if unexpected
    bool fast = false;
#if HAVE_PLSWAP
    {
        int lane = tid & 63;
        uint2v pr = __builtin_amdgcn_permlane16_swap((unsigned)lane, (unsigned)lane, false, false);
        unsigned got = ((lane & 16) == 0) ? pr.y : pr.x;
        bool ok1 = (got == (unsigned)(lane ^ 16));
        int t = __builtin_amdgcn_update_dpp(0, lane, 0x142, 0xF, 0xF, false);
        uint2v pb = __builtin_amdgcn_permlane16_swap((unsigned)t, (unsigned)t, false, false);
        bool ok2 = (pb.y == (unsigned)(15 + (lane & 32)));
        fast = __all(ok1 && ok2);
    }
#endif

    float logC;
    float u;
    if (fast) u = run_scan<true>(eptr, Eo, Ex, tag, sel_even, logC);
    else      u = run_scan<false>(eptr, Eo, Ex, tag, sel_even, logC);

    // alpha_T = log(u) + logC; terminal lse over the 32-lane group (DS ok — once)
    float alpha = __logf(u) + logC;
    float t = alpha + tEOS;
    float mx = t;
    mx = fmaxf(mx, swz_xor<1>(mx));
    mx = fmaxf(mx, swz_xor<2>(mx));
    mx = fmaxf(mx, swz_xor<4>(mx));
    mx = fmaxf(mx, swz_xor<8>(mx));
    mx = fmaxf(mx, swz_xor<16>(mx));
    float s = __expf(t - mx);
    s += swz_xor<1>(s);
    s += swz_xor<2>(s);
    s += swz_xor<4>(s);
    s += swz_xor<8>(s);
    s += swz_xor<16>(s);
    float res = mx + __logf(s);
    if (tag == 0) out[b] = res;
}

extern "C" void kernel_launch(void* const* d_in, const int* in_sizes, int n_in,
                              void* d_out, int out_size, void* d_ws, size_t ws_size,
                              hipStream_t stream) {
    const float* em = (const float*)d_in[0];
    const float* tr = (const float*)d_in[1];
    float* out = (float*)d_out;

    const int T = 512;
    const int B = in_sizes[0] / (T * KTAGS);  // 2048
    const int blocks = B / 8;                 // 256 blocks x 256 threads

    crf_fwd_kernel<<<blocks, 256, 0, stream>>>(em, tr, out, T);
}